// Round 1
// baseline (13777.582 us; speedup 1.0000x reference)
//
#include <hip/hip_runtime.h>

#define BB 32
#define TT 40
#define TS 39
#define VV 8000
#define EE 50
#define HH 2048

__device__ __forceinline__ float sigmf(float x) { return 1.0f / (1.0f + __expf(-x)); }
__device__ __forceinline__ float tanhf_fast(float x) { return 2.0f / (1.0f + __expf(-2.0f * x)) - 1.0f; }

// ---------------------------------------------------------------------------
// Phase A: xw[t][b][j] = emb[captions[b][t]] . Wih[j][:] + bih[j] + bhh[j]
// grid: (4H/256, TS), block 256. Each block: one t, 256 j's, all 32 b.
// ---------------------------------------------------------------------------
__global__ void embed_proj_kernel(const int* __restrict__ caps,
                                  const float* __restrict__ emb,
                                  const float* __restrict__ Wih,
                                  const float* __restrict__ bih,
                                  const float* __restrict__ bhh,
                                  float* __restrict__ xw) {
    __shared__ float elds[BB][EE];
    int t = blockIdx.y;
    int j = blockIdx.x * 256 + threadIdx.x;
    for (int idx = threadIdx.x; idx < BB * EE; idx += 256) {
        int bl = idx / EE, e = idx - bl * EE;
        elds[bl][e] = emb[(size_t)caps[bl * TT + t] * EE + e];
    }
    __syncthreads();
    float wreg[EE];
#pragma unroll
    for (int e = 0; e < EE; ++e) wreg[e] = Wih[(size_t)j * EE + e];
    float bias = bih[j] + bhh[j];
    for (int bl = 0; bl < BB; ++bl) {
        float acc = bias;
#pragma unroll
        for (int e = 0; e < EE; ++e) acc += wreg[e] * elds[bl][e];
        xw[((size_t)(t * BB + bl)) * (4 * HH) + j] = acc;
    }
}

// ---------------------------------------------------------------------------
// Init: transpose features [32][2048] -> hT/cT/hgT [2048][32]
// ---------------------------------------------------------------------------
__global__ void init_state_kernel(const float* __restrict__ feat,
                                  float* __restrict__ hT,
                                  float* __restrict__ cT,
                                  float* __restrict__ hgT) {
    int i = blockIdx.x * 256 + threadIdx.x;   // coalesced read over [b][k]
    int b = i >> 11;       // /HH
    int k = i & (HH - 1);
    float v = feat[i];
    hT[k * BB + b] = v;
    cT[k * BB + b] = v;
    hgT[k * BB + b] = v;
}

// ---------------------------------------------------------------------------
// Step stage 1 (one launch): blocks [0,256): LSTM gate-group per (b,kk):
//   4 dots over hT_in, fused activations -> cT (in-place), hT_out.
// blocks [256,512): GRU gh rows {kk,H+kk,2H+kk} over hgT -> ghT raw (+gbhh).
// grid 512 x 256 threads; lanes: b = tid&31 (fast), kk = tid>>5.
// ---------------------------------------------------------------------------
__global__ void step1_kernel(const float* __restrict__ Whh,
                             const float* __restrict__ gWhh,
                             const float* __restrict__ gbhh,
                             const float* __restrict__ xw_t,
                             const float* __restrict__ hT_in,
                             const float* __restrict__ hgT,
                             float* __restrict__ hT_out,
                             float* __restrict__ cT,
                             float* __restrict__ ghT) {
    int gid = blockIdx.x * 256 + threadIdx.x;
    if (gid < BB * HH) {
        int b = gid & 31, kk = gid >> 5;
        const float* wi = Whh + (size_t)kk * HH;
        const float* wf = Whh + (size_t)(HH + kk) * HH;
        const float* wg = Whh + (size_t)(2 * HH + kk) * HH;
        const float* wo = Whh + (size_t)(3 * HH + kk) * HH;
        const float* hp = hT_in + b;
        float ai = 0.f, af = 0.f, ag = 0.f, ao = 0.f;
        for (int k = 0; k < HH; k += 4) {
            float4 vi = *(const float4*)(wi + k);
            float4 vf = *(const float4*)(wf + k);
            float4 vg = *(const float4*)(wg + k);
            float4 vo = *(const float4*)(wo + k);
            float h0 = hp[(k + 0) * BB];
            float h1 = hp[(k + 1) * BB];
            float h2 = hp[(k + 2) * BB];
            float h3 = hp[(k + 3) * BB];
            ai += vi.x * h0 + vi.y * h1 + vi.z * h2 + vi.w * h3;
            af += vf.x * h0 + vf.y * h1 + vf.z * h2 + vf.w * h3;
            ag += vg.x * h0 + vg.y * h1 + vg.z * h2 + vg.w * h3;
            ao += vo.x * h0 + vo.y * h1 + vo.z * h2 + vo.w * h3;
        }
        const float* xwb = xw_t + (size_t)b * 4 * HH + kk;
        ai += xwb[0];
        af += xwb[HH];
        ag += xwb[2 * HH];
        ao += xwb[3 * HH];
        float c = sigmf(af) * cT[kk * BB + b] + sigmf(ai) * tanhf_fast(ag);
        float h = sigmf(ao) * tanhf_fast(c);
        cT[kk * BB + b] = c;          // only this thread touches this element
        hT_out[kk * BB + b] = h;
    } else {
        int id = gid - BB * HH;
        int b = id & 31, kk = id >> 5;
        const float* wr = gWhh + (size_t)kk * HH;
        const float* wz = gWhh + (size_t)(HH + kk) * HH;
        const float* wn = gWhh + (size_t)(2 * HH + kk) * HH;
        const float* hp = hgT + b;
        float ar = 0.f, az = 0.f, an = 0.f;
        for (int k = 0; k < HH; k += 4) {
            float4 vr = *(const float4*)(wr + k);
            float4 vz = *(const float4*)(wz + k);
            float4 vn = *(const float4*)(wn + k);
            float h0 = hp[(k + 0) * BB];
            float h1 = hp[(k + 1) * BB];
            float h2 = hp[(k + 2) * BB];
            float h3 = hp[(k + 3) * BB];
            ar += vr.x * h0 + vr.y * h1 + vr.z * h2 + vr.w * h3;
            az += vz.x * h0 + vz.y * h1 + vz.z * h2 + vz.w * h3;
            an += vn.x * h0 + vn.y * h1 + vn.z * h2 + vn.w * h3;
        }
        ghT[(size_t)kk * BB + b] = ar + gbhh[kk];
        ghT[(size_t)(HH + kk) * BB + b] = az + gbhh[HH + kk];
        ghT[(size_t)(2 * HH + kk) * BB + b] = an + gbhh[2 * HH + kk];
    }
}

// ---------------------------------------------------------------------------
// Step stage 2: gi rows {kk,H+kk,2H+kk} over cT (post-LSTM), fused GRU
// activations -> hgT (in-place elementwise) and hg_all[t][b][k].
// grid 256 x 256.
// ---------------------------------------------------------------------------
__global__ void step2_kernel(const float* __restrict__ gWih,
                             const float* __restrict__ gbih,
                             const float* __restrict__ cT,
                             const float* __restrict__ ghT,
                             float* __restrict__ hgT,
                             float* __restrict__ hg_all_t) {
    int gid = blockIdx.x * 256 + threadIdx.x;
    int b = gid & 31, kk = gid >> 5;
    const float* wr = gWih + (size_t)kk * HH;
    const float* wz = gWih + (size_t)(HH + kk) * HH;
    const float* wn = gWih + (size_t)(2 * HH + kk) * HH;
    const float* cp = cT + b;
    float ar = 0.f, az = 0.f, an = 0.f;
    for (int k = 0; k < HH; k += 4) {
        float4 vr = *(const float4*)(wr + k);
        float4 vz = *(const float4*)(wz + k);
        float4 vn = *(const float4*)(wn + k);
        float c0 = cp[(k + 0) * BB];
        float c1 = cp[(k + 1) * BB];
        float c2 = cp[(k + 2) * BB];
        float c3 = cp[(k + 3) * BB];
        ar += vr.x * c0 + vr.y * c1 + vr.z * c2 + vr.w * c3;
        az += vz.x * c0 + vz.y * c1 + vz.z * c2 + vz.w * c3;
        an += vn.x * c0 + vn.y * c1 + vn.z * c2 + vn.w * c3;
    }
    float r = sigmf(ar + gbih[kk] + ghT[(size_t)kk * BB + b]);
    float z = sigmf(az + gbih[HH + kk] + ghT[(size_t)(HH + kk) * BB + b]);
    float n = tanhf_fast(an + gbih[2 * HH + kk] + r * ghT[(size_t)(2 * HH + kk) * BB + b]);
    float hgp = hgT[kk * BB + b];
    float hg = (1.f - z) * n + z * hgp;
    hgT[kk * BB + b] = hg;
    hg_all_t[(size_t)b * HH + kk] = hg;
}

// ---------------------------------------------------------------------------
// Phase C: out[b][t][v] = hg_all[t*B+b][:] . lin_W[v][:] + lin_b[v]
// Tiled fp32 GEMM: M=1248 (t*32+b), N=8000, K=2048.
// Tile 64x64 per 256-thread block, 4x4 per thread, KC=16.
// grid (8000/64=125, ceil(1248/64)=20)
// ---------------------------------------------------------------------------
__global__ void out_gemm_kernel(const float* __restrict__ A,    // [1248][2048]
                                const float* __restrict__ Wl,   // [8000][2048]
                                const float* __restrict__ bl,
                                float* __restrict__ out) {
    __shared__ float As[16][68];
    __shared__ float Bs[16][68];
    int nt = blockIdx.x, mt = blockIdx.y;
    int tid = threadIdx.x;
    int kl = tid & 15;        // staging: k within chunk
    int ml = tid >> 4;        // staging: 16 groups of 4 rows
    int tx = tid & 15;        // compute: n-quad
    int ty = tid >> 4;        // compute: m-quad
    float acc[4][4];
#pragma unroll
    for (int i = 0; i < 4; ++i)
#pragma unroll
        for (int j = 0; j < 4; ++j) acc[i][j] = 0.f;

    for (int k0 = 0; k0 < HH; k0 += 16) {
#pragma unroll
        for (int i = 0; i < 4; ++i) {
            int m = mt * 64 + ml * 4 + i;
            As[kl][ml * 4 + i] = (m < TS * BB) ? A[(size_t)m * HH + k0 + kl] : 0.f;
            int n = nt * 64 + ml * 4 + i;
            Bs[kl][ml * 4 + i] = Wl[(size_t)n * HH + k0 + kl];
        }
        __syncthreads();
#pragma unroll
        for (int k = 0; k < 16; ++k) {
            float a0 = As[k][ty * 4 + 0], a1 = As[k][ty * 4 + 1];
            float a2 = As[k][ty * 4 + 2], a3 = As[k][ty * 4 + 3];
            float b0 = Bs[k][tx * 4 + 0], b1 = Bs[k][tx * 4 + 1];
            float b2 = Bs[k][tx * 4 + 2], b3 = Bs[k][tx * 4 + 3];
            acc[0][0] += a0 * b0; acc[0][1] += a0 * b1; acc[0][2] += a0 * b2; acc[0][3] += a0 * b3;
            acc[1][0] += a1 * b0; acc[1][1] += a1 * b1; acc[1][2] += a1 * b2; acc[1][3] += a1 * b3;
            acc[2][0] += a2 * b0; acc[2][1] += a2 * b1; acc[2][2] += a2 * b2; acc[2][3] += a2 * b3;
            acc[3][0] += a3 * b0; acc[3][1] += a3 * b1; acc[3][2] += a3 * b2; acc[3][3] += a3 * b3;
        }
        __syncthreads();
    }
#pragma unroll
    for (int i = 0; i < 4; ++i) {
        int m = mt * 64 + ty * 4 + i;
        if (m < TS * BB) {
            int t = m >> 5, b = m & 31;
            size_t base = ((size_t)b * TS + t) * VV;
#pragma unroll
            for (int j = 0; j < 4; ++j) {
                int n = nt * 64 + tx * 4 + j;
                out[base + n] = acc[i][j] + bl[n];
            }
        }
    }
}

// ---------------------------------------------------------------------------
extern "C" void kernel_launch(void* const* d_in, const int* in_sizes, int n_in,
                              void* d_out, int out_size, void* d_ws, size_t ws_size,
                              hipStream_t stream) {
    const float* features = (const float*)d_in[0];
    const int*   captions = (const int*)d_in[1];
    const float* emb      = (const float*)d_in[2];
    const float* lstm_Wih = (const float*)d_in[3];
    const float* lstm_bih = (const float*)d_in[4];
    const float* lstm_Whh = (const float*)d_in[5];
    const float* lstm_bhh = (const float*)d_in[6];
    const float* gru_Wih  = (const float*)d_in[7];
    const float* gru_bih  = (const float*)d_in[8];
    const float* gru_Whh  = (const float*)d_in[9];
    const float* gru_bhh  = (const float*)d_in[10];
    const float* lin_W    = (const float*)d_in[11];
    const float* lin_b    = (const float*)d_in[12];
    float* out = (float*)d_out;

    float* ws = (float*)d_ws;
    float* xw     = ws;                                  // TS*BB*4H = 10,223,616
    float* hT0    = xw + (size_t)TS * BB * 4 * HH;       // 65536
    float* hT1    = hT0 + BB * HH;                       // 65536
    float* cT     = hT1 + BB * HH;                       // 65536
    float* hgT    = cT + BB * HH;                        // 65536
    float* ghT    = hgT + BB * HH;                       // 3*H*B = 196608
    float* hg_all = ghT + (size_t)3 * HH * BB;           // TS*BB*H = 2,555,904

    embed_proj_kernel<<<dim3(4 * HH / 256, TS), 256, 0, stream>>>(
        captions, emb, lstm_Wih, lstm_bih, lstm_bhh, xw);
    init_state_kernel<<<(BB * HH) / 256, 256, 0, stream>>>(features, hT0, cT, hgT);

    for (int t = 0; t < TS; ++t) {
        const float* hin = (t & 1) ? hT1 : hT0;
        float*       hout = (t & 1) ? hT0 : hT1;
        step1_kernel<<<512, 256, 0, stream>>>(
            lstm_Whh, gru_Whh, gru_bhh, xw + (size_t)t * BB * 4 * HH,
            hin, hgT, hout, cT, ghT);
        step2_kernel<<<256, 256, 0, stream>>>(
            gru_Wih, gru_bih, cT, ghT, hgT, hg_all + (size_t)t * BB * HH);
    }

    out_gemm_kernel<<<dim3(VV / 64, (TS * BB + 63) / 64), 256, 0, stream>>>(
        hg_all, lin_W, lin_b, out);
}

// Round 2
// 2092.836 us; speedup vs baseline: 6.5832x; 6.5832x over previous
//
#include <hip/hip_runtime.h>

#define BB 32
#define TT 40
#define TS 39
#define VV 8000
#define EE 50
#define HH 2048

typedef short s16x8 __attribute__((ext_vector_type(8)));
typedef float f32x4 __attribute__((ext_vector_type(4)));

__device__ __forceinline__ float sigmf(float x) { return 1.0f / (1.0f + __expf(-x)); }
__device__ __forceinline__ float tanhf_fast(float x) { return 2.0f / (1.0f + __expf(-2.0f * x)) - 1.0f; }

__device__ __forceinline__ unsigned short f2bf(float x) {
    union { float f; unsigned u; } v; v.f = x;
    unsigned r = v.u + 0x7FFF + ((v.u >> 16) & 1);   // RNE
    return (unsigned short)(r >> 16);
}

// ---------------------------------------------------------------------------
// fp32 -> bf16 weight conversion, 4 elems/thread
// ---------------------------------------------------------------------------
__global__ void convert_kernel(const float* __restrict__ src,
                               unsigned short* __restrict__ dst, int n4) {
    int i = blockIdx.x * 256 + threadIdx.x;
    if (i < n4) {
        float4 v = ((const float4*)src)[i];
        ushort4 o;
        o.x = f2bf(v.x); o.y = f2bf(v.y); o.z = f2bf(v.z); o.w = f2bf(v.w);
        ((ushort4*)dst)[i] = o;
    }
}

// ---------------------------------------------------------------------------
// Phase A: xw[t][b][j] = emb[captions[b][t]] . Wih[j][:] + bih[j] + bhh[j]
// ---------------------------------------------------------------------------
__global__ void embed_proj_kernel(const int* __restrict__ caps,
                                  const float* __restrict__ emb,
                                  const float* __restrict__ Wih,
                                  const float* __restrict__ bih,
                                  const float* __restrict__ bhh,
                                  float* __restrict__ xw) {
    __shared__ float elds[BB][EE];
    int t = blockIdx.y;
    int j = blockIdx.x * 256 + threadIdx.x;
    for (int idx = threadIdx.x; idx < BB * EE; idx += 256) {
        int bl = idx / EE, e = idx - bl * EE;
        elds[bl][e] = emb[(size_t)caps[bl * TT + t] * EE + e];
    }
    __syncthreads();
    float wreg[EE];
#pragma unroll
    for (int e = 0; e < EE; ++e) wreg[e] = Wih[(size_t)j * EE + e];
    float bias = bih[j] + bhh[j];
    for (int bl = 0; bl < BB; ++bl) {
        float acc = bias;
#pragma unroll
        for (int e = 0; e < EE; ++e) acc += wreg[e] * elds[bl][e];
        xw[((size_t)(t * BB + bl)) * (4 * HH) + j] = acc;
    }
}

// ---------------------------------------------------------------------------
// Init: states in [b][k] layout. fp32 masters for c/hg, bf16 copies for MFMA.
// ---------------------------------------------------------------------------
__global__ void init_state_kernel(const float* __restrict__ feat,
                                  float* __restrict__ c32, float* __restrict__ hg32,
                                  unsigned short* __restrict__ hbf,
                                  unsigned short* __restrict__ cbf,
                                  unsigned short* __restrict__ hgbf) {
    int i = blockIdx.x * 256 + threadIdx.x;    // 65536 threads
    float v = feat[i];
    c32[i] = v; hg32[i] = v;
    unsigned short b = f2bf(v);
    hbf[i] = b; cbf[i] = b; hgbf[i] = b;
}

// ---------------------------------------------------------------------------
// step1: blocks [0,128): LSTM — 16 kk x 4 gates, split-K x2, fused activation.
//        blocks [128,224): GRU gh — 64 rows, raw + bias into gh.
// 512 threads = 8 waves: wave = (g, kh). Each wave: 16x16 tile x 2 m-halves,
// K-chunk 1024 (32 iters of k-step 32), 2 MFMA/iter.
// MFMA layouts (m89/m91-verified): A lane l: A[m=l&15][k=(l>>4)*8+j];
// B lane l: B[k=(l>>4)*8+j][n=l&15] = W[n][k]; D: col=l&15, row=(l>>4)*4+reg.
// ---------------------------------------------------------------------------
__global__ __launch_bounds__(512) void step1_kernel(
    const unsigned short* __restrict__ Whh,    // [8192][2048] bf16
    const unsigned short* __restrict__ gWhh,   // [6144][2048] bf16
    const float* __restrict__ gbhh,            // [6144]
    const float* __restrict__ xw_t,            // [32][8192]
    const unsigned short* __restrict__ hbf_in, // [32][2048]
    const unsigned short* __restrict__ hgbf,   // [32][2048]
    float* __restrict__ c32,                   // [32][2048] in/out
    unsigned short* __restrict__ cbf,          // [32][2048] out
    unsigned short* __restrict__ hbf_out,      // [32][2048] out
    float* __restrict__ gh)                    // [32][6144] out (raw + bhh)
{
    __shared__ float lsum[4][2][32][17];
    const int tid = threadIdx.x;
    const int lane = tid & 63;
    const int w = tid >> 6;       // 0..7
    const int g = w >> 1;         // gate / n-subtile
    const int kh = w & 1;         // K half
    const int l15 = lane & 15;
    const int lq = lane >> 4;     // 0..3
    const int kofs = kh * 1024 + lq * 8;

    const bool lstm = (blockIdx.x < 128);
    const unsigned short* Abase;
    const unsigned short* Brow;
    if (lstm) {
        int kk0 = blockIdx.x * 16;
        Brow = Whh + (size_t)(g * HH + kk0 + l15) * HH + kofs;
        Abase = hbf_in;
    } else {
        int n0 = (blockIdx.x - 128) * 64;
        Brow = gWhh + (size_t)(n0 + g * 16 + l15) * HH + kofs;
        Abase = hgbf;
    }
    const unsigned short* Arow0 = Abase + l15 * HH + kofs;
    const unsigned short* Arow1 = Arow0 + 16 * HH;

    f32x4 acc0 = {0.f, 0.f, 0.f, 0.f};
    f32x4 acc1 = {0.f, 0.f, 0.f, 0.f};
#pragma unroll 4
    for (int it = 0; it < 32; ++it) {
        s16x8 bv = *(const s16x8*)(Brow + it * 32);
        s16x8 a0 = *(const s16x8*)(Arow0 + it * 32);
        s16x8 a1 = *(const s16x8*)(Arow1 + it * 32);
        acc0 = __builtin_amdgcn_mfma_f32_16x16x32_bf16(a0, bv, acc0, 0, 0, 0);
        acc1 = __builtin_amdgcn_mfma_f32_16x16x32_bf16(a1, bv, acc1, 0, 0, 0);
    }
#pragma unroll
    for (int r = 0; r < 4; ++r) {
        lsum[g][kh][lq * 4 + r][l15]      = acc0[r];   // m = batch, n = row-in-tile
        lsum[g][kh][16 + lq * 4 + r][l15] = acc1[r];
    }
    __syncthreads();

    if (lstm) {
        int kk0 = blockIdx.x * 16;
        int kkl = tid & 15, b = tid >> 4;              // 512 threads = 32b x 16kk
        int kk = kk0 + kkl;
        const float* xwb = xw_t + (size_t)b * 4 * HH;
        float vi = lsum[0][0][b][kkl] + lsum[0][1][b][kkl] + xwb[kk];
        float vf = lsum[1][0][b][kkl] + lsum[1][1][b][kkl] + xwb[HH + kk];
        float vg = lsum[2][0][b][kkl] + lsum[2][1][b][kkl] + xwb[2 * HH + kk];
        float vo = lsum[3][0][b][kkl] + lsum[3][1][b][kkl] + xwb[3 * HH + kk];
        int idx = b * HH + kk;
        float c = sigmf(vf) * c32[idx] + sigmf(vi) * tanhf_fast(vg);
        float h = sigmf(vo) * tanhf_fast(c);
        c32[idx] = c;
        cbf[idx] = f2bf(c);
        hbf_out[idx] = f2bf(h);
    } else {
        int n0 = (blockIdx.x - 128) * 64;
        for (int cell = tid; cell < 2048; cell += 512) {
            int nl = cell & 63, b = cell >> 6;
            int n = n0 + nl;
            float v = lsum[nl >> 4][0][b][nl & 15] + lsum[nl >> 4][1][b][nl & 15] + gbhh[n];
            gh[b * 3 * HH + n] = v;
        }
    }
}

// ---------------------------------------------------------------------------
// step2: gi = cbf @ gWih.T, 16 kk x 3 gates per block, split-K x2,
// fused GRU epilogue. 384 threads = 6 waves.
// ---------------------------------------------------------------------------
__global__ __launch_bounds__(384) void step2_kernel(
    const unsigned short* __restrict__ gWih,   // [6144][2048] bf16
    const float* __restrict__ gbih,            // [6144]
    const unsigned short* __restrict__ cbf,    // [32][2048]
    const float* __restrict__ gh,              // [32][6144]
    float* __restrict__ hg32,                  // [32][2048] in/out
    unsigned short* __restrict__ hgbf,         // [32][2048] out
    unsigned short* __restrict__ hg_all_t)     // rows b: hg_all[(t*32+b)][k]
{
    __shared__ float lsum[3][2][32][17];
    const int tid = threadIdx.x;
    const int lane = tid & 63;
    const int w = tid >> 6;       // 0..5
    const int g = w >> 1;         // 0..2 (r,z,n)
    const int kh = w & 1;
    const int l15 = lane & 15;
    const int lq = lane >> 4;
    const int kofs = kh * 1024 + lq * 8;
    const int kk0 = blockIdx.x * 16;

    const unsigned short* Arow0 = cbf + l15 * HH + kofs;
    const unsigned short* Arow1 = Arow0 + 16 * HH;
    const unsigned short* Brow = gWih + (size_t)(g * HH + kk0 + l15) * HH + kofs;

    f32x4 acc0 = {0.f, 0.f, 0.f, 0.f};
    f32x4 acc1 = {0.f, 0.f, 0.f, 0.f};
#pragma unroll 4
    for (int it = 0; it < 32; ++it) {
        s16x8 bv = *(const s16x8*)(Brow + it * 32);
        s16x8 a0 = *(const s16x8*)(Arow0 + it * 32);
        s16x8 a1 = *(const s16x8*)(Arow1 + it * 32);
        acc0 = __builtin_amdgcn_mfma_f32_16x16x32_bf16(a0, bv, acc0, 0, 0, 0);
        acc1 = __builtin_amdgcn_mfma_f32_16x16x32_bf16(a1, bv, acc1, 0, 0, 0);
    }
#pragma unroll
    for (int r = 0; r < 4; ++r) {
        lsum[g][kh][lq * 4 + r][l15]      = acc0[r];
        lsum[g][kh][16 + lq * 4 + r][l15] = acc1[r];
    }
    __syncthreads();

    for (int cell = tid; cell < 512; cell += 384) {
        int kkl = cell & 15, b = cell >> 4;
        int kk = kk0 + kkl;
        float ri = lsum[0][0][b][kkl] + lsum[0][1][b][kkl] + gbih[kk];
        float zi = lsum[1][0][b][kkl] + lsum[1][1][b][kkl] + gbih[HH + kk];
        float ni = lsum[2][0][b][kkl] + lsum[2][1][b][kkl] + gbih[2 * HH + kk];
        const float* ghb = gh + b * 3 * HH;
        float r = sigmf(ri + ghb[kk]);
        float z = sigmf(zi + ghb[HH + kk]);
        float n = tanhf_fast(ni + r * ghb[2 * HH + kk]);
        int idx = b * HH + kk;
        float hgn = (1.f - z) * n + z * hg32[idx];
        hg32[idx] = hgn;
        unsigned short hb = f2bf(hgn);
        hgbf[idx] = hb;
        hg_all_t[idx] = hb;
    }
}

// ---------------------------------------------------------------------------
// Phase C: out = hg_all @ linW.T + b. bf16 MFMA, 64x64 tile, BK=32, LDS-staged.
// grid (125, 20), 256 threads = 4 waves (wave = m-subtile).
// ---------------------------------------------------------------------------
__global__ __launch_bounds__(256) void out_gemm_kernel(
    const unsigned short* __restrict__ A,     // [1280][2048] (rows >=1248 junk)
    const unsigned short* __restrict__ Wl,    // [8000][2048]
    const float* __restrict__ bl,
    float* __restrict__ out) {
    __shared__ unsigned short As[64][40];     // pad 32->40 bf16 (bank spread)
    __shared__ unsigned short Bs[64][40];
    const int tid = threadIdx.x;
    const int lane = tid & 63;
    const int w = tid >> 6;
    const int l15 = lane & 15;
    const int lq = lane >> 4;
    const int nt = blockIdx.x, mt = blockIdx.y;
    const int srow = tid >> 2, scol = (tid & 3) * 8;
    const unsigned short* Ap = A + (size_t)(mt * 64 + srow) * HH + scol;
    const unsigned short* Bp = Wl + (size_t)(nt * 64 + srow) * HH + scol;

    f32x4 acc[4];
#pragma unroll
    for (int i = 0; i < 4; ++i) acc[i] = (f32x4){0.f, 0.f, 0.f, 0.f};

    for (int k0 = 0; k0 < HH; k0 += 32) {
        s16x8 av = *(const s16x8*)(Ap + k0);
        s16x8 bv = *(const s16x8*)(Bp + k0);
        *(s16x8*)&As[srow][scol] = av;
        *(s16x8*)&Bs[srow][scol] = bv;
        __syncthreads();
        s16x8 af = *(const s16x8*)&As[w * 16 + l15][lq * 8];
#pragma unroll
        for (int ns = 0; ns < 4; ++ns) {
            s16x8 bf = *(const s16x8*)&Bs[ns * 16 + l15][lq * 8];
            acc[ns] = __builtin_amdgcn_mfma_f32_16x16x32_bf16(af, bf, acc[ns], 0, 0, 0);
        }
        __syncthreads();
    }
#pragma unroll
    for (int ns = 0; ns < 4; ++ns) {
        int n = nt * 64 + ns * 16 + l15;
        float bn = bl[n];
#pragma unroll
        for (int r = 0; r < 4; ++r) {
            int m = mt * 64 + w * 16 + lq * 4 + r;
            if (m < TS * BB) {
                int t = m >> 5, b = m & 31;
                out[((size_t)b * TS + t) * VV + n] = acc[ns][r] + bn;
            }
        }
    }
}

// ---------------------------------------------------------------------------
extern "C" void kernel_launch(void* const* d_in, const int* in_sizes, int n_in,
                              void* d_out, int out_size, void* d_ws, size_t ws_size,
                              hipStream_t stream) {
    const float* features = (const float*)d_in[0];
    const int*   captions = (const int*)d_in[1];
    const float* emb      = (const float*)d_in[2];
    const float* lstm_Wih = (const float*)d_in[3];
    const float* lstm_bih = (const float*)d_in[4];
    const float* lstm_Whh = (const float*)d_in[5];
    const float* lstm_bhh = (const float*)d_in[6];
    const float* gru_Wih  = (const float*)d_in[7];
    const float* gru_bih  = (const float*)d_in[8];
    const float* gru_Whh  = (const float*)d_in[9];
    const float* gru_bhh  = (const float*)d_in[10];
    const float* lin_W    = (const float*)d_in[11];
    const float* lin_b    = (const float*)d_in[12];
    float* out = (float*)d_out;

    // workspace layout (bf16 section first, then fp32) — ~165 MB total
    unsigned short* us = (unsigned short*)d_ws;
    unsigned short* Whh_bf  = us;                              // 8192*2048
    unsigned short* gWhh_bf = Whh_bf  + (size_t)8192 * HH;     // 6144*2048
    unsigned short* gWih_bf = gWhh_bf + (size_t)6144 * HH;     // 6144*2048
    unsigned short* linW_bf = gWih_bf + (size_t)6144 * HH;     // 8000*2048
    unsigned short* hbf0    = linW_bf + (size_t)VV * HH;
    unsigned short* hbf1    = hbf0 + BB * HH;
    unsigned short* cbf     = hbf1 + BB * HH;
    unsigned short* hgbf    = cbf  + BB * HH;
    unsigned short* hg_all  = hgbf + BB * HH;                  // 1280*2048 (padded)
    float* f32s = (float*)(hg_all + (size_t)1280 * HH);
    float* xw   = f32s;                                        // 39*32*8192
    float* c32  = xw + (size_t)TS * BB * 4 * HH;
    float* hg32 = c32 + BB * HH;
    float* gh   = hg32 + BB * HH;                              // 32*6144

    // 1) weight conversion (d_ws is re-poisoned before every call)
    {
        int n4;
        n4 = 8192 * HH / 4;
        convert_kernel<<<(n4 + 255) / 256, 256, 0, stream>>>(lstm_Whh, Whh_bf, n4);
        n4 = 6144 * HH / 4;
        convert_kernel<<<(n4 + 255) / 256, 256, 0, stream>>>(gru_Whh, gWhh_bf, n4);
        convert_kernel<<<(n4 + 255) / 256, 256, 0, stream>>>(gru_Wih, gWih_bf, n4);
        n4 = VV * HH / 4;
        convert_kernel<<<(n4 + 255) / 256, 256, 0, stream>>>(lin_W, linW_bf, n4);
    }

    // 2) precompute x-side gate biases for all steps
    embed_proj_kernel<<<dim3(4 * HH / 256, TS), 256, 0, stream>>>(
        captions, emb, lstm_Wih, lstm_bih, lstm_bhh, xw);

    // 3) init states
    init_state_kernel<<<(BB * HH) / 256, 256, 0, stream>>>(
        features, c32, hg32, hbf0, cbf, hgbf);

    // 4) recurrence
    for (int t = 0; t < TS; ++t) {
        const unsigned short* hin = (t & 1) ? hbf1 : hbf0;
        unsigned short*       hout = (t & 1) ? hbf0 : hbf1;
        step1_kernel<<<224, 512, 0, stream>>>(
            Whh_bf, gWhh_bf, gru_bhh, xw + (size_t)t * BB * 4 * HH,
            hin, hgbf, c32, cbf, hout, gh);
        step2_kernel<<<128, 384, 0, stream>>>(
            gWih_bf, gru_bih, cbf, gh, hg32, hgbf, hg_all + (size_t)t * BB * HH);
    }

    // 5) output projection
    out_gemm_kernel<<<dim3(VV / 64, (TS * BB + 63) / 64), 256, 0, stream>>>(
        hg_all, linW_bf, lin_b, out);
}

// Round 3
// 2054.264 us; speedup vs baseline: 6.7068x; 1.0188x over previous
//
#include <hip/hip_runtime.h>

#define BB 32
#define TT 40
#define TS 39
#define VV 8000
#define EE 50
#define HH 2048

typedef short s16x8 __attribute__((ext_vector_type(8)));
typedef float f32x4 __attribute__((ext_vector_type(4)));

__device__ __forceinline__ float sigmf(float x) { return 1.0f / (1.0f + __expf(-x)); }
__device__ __forceinline__ float tanhf_fast(float x) { return 2.0f / (1.0f + __expf(-2.0f * x)) - 1.0f; }

__device__ __forceinline__ unsigned short f2bf(float x) {
    union { float f; unsigned u; } v; v.f = x;
    unsigned r = v.u + 0x7FFF + ((v.u >> 16) & 1);   // RNE
    return (unsigned short)(r >> 16);
}

// ---------------------------------------------------------------------------
// fp32 -> bf16 weight conversion, 4 elems/thread
// ---------------------------------------------------------------------------
__global__ void convert_kernel(const float* __restrict__ src,
                               unsigned short* __restrict__ dst, int n4) {
    int i = blockIdx.x * 256 + threadIdx.x;
    if (i < n4) {
        float4 v = ((const float4*)src)[i];
        ushort4 o;
        o.x = f2bf(v.x); o.y = f2bf(v.y); o.z = f2bf(v.z); o.w = f2bf(v.w);
        ((ushort4*)dst)[i] = o;
    }
}

// ---------------------------------------------------------------------------
// Phase A: xw[t][b][j] = emb[captions[b][t]] . Wih[j][:] + bih[j] + bhh[j]
// ---------------------------------------------------------------------------
__global__ void embed_proj_kernel(const int* __restrict__ caps,
                                  const float* __restrict__ emb,
                                  const float* __restrict__ Wih,
                                  const float* __restrict__ bih,
                                  const float* __restrict__ bhh,
                                  float* __restrict__ xw) {
    __shared__ float elds[BB][EE];
    int t = blockIdx.y;
    int j = blockIdx.x * 256 + threadIdx.x;
    for (int idx = threadIdx.x; idx < BB * EE; idx += 256) {
        int bl = idx / EE, e = idx - bl * EE;
        elds[bl][e] = emb[(size_t)caps[bl * TT + t] * EE + e];
    }
    __syncthreads();
    float wreg[EE];
#pragma unroll
    for (int e = 0; e < EE; ++e) wreg[e] = Wih[(size_t)j * EE + e];
    float bias = bih[j] + bhh[j];
    for (int bl = 0; bl < BB; ++bl) {
        float acc = bias;
#pragma unroll
        for (int e = 0; e < EE; ++e) acc += wreg[e] * elds[bl][e];
        xw[((size_t)(t * BB + bl)) * (4 * HH) + j] = acc;
    }
}

// ---------------------------------------------------------------------------
// Init: states in [b][k] layout. fp32 masters for c/hg, bf16 copies for MFMA.
// ---------------------------------------------------------------------------
__global__ void init_state_kernel(const float* __restrict__ feat,
                                  float* __restrict__ c32, float* __restrict__ hg32,
                                  unsigned short* __restrict__ hbf,
                                  unsigned short* __restrict__ cbf,
                                  unsigned short* __restrict__ hgbf) {
    int i = blockIdx.x * 256 + threadIdx.x;    // 65536 threads
    float v = feat[i];
    c32[i] = v; hg32[i] = v;
    unsigned short b = f2bf(v);
    hbf[i] = b; cbf[i] = b; hgbf[i] = b;
}

// ---------------------------------------------------------------------------
// step1: blocks [0,128): LSTM — one 16-kk strip, 4 gates x 4 K-quarters
//        (16 waves), fused LSTM activation epilogue.
//        blocks [128,224): GRU gh — 64 rows (4 strips) x 4 K-quarters.
// 1024 threads = 16 waves. wave w: (g = w>>2, kh = w&3). K window 512/wave,
// 16 iters of k-step 32, 2 MFMA/iter (batch halves).
// MFMA layouts (m89/m91-verified, identical to the round-2 passing kernel).
// ---------------------------------------------------------------------------
__global__ __launch_bounds__(1024, 4) void step1_kernel(
    const unsigned short* __restrict__ Whh,    // [8192][2048] bf16
    const unsigned short* __restrict__ gWhh,   // [6144][2048] bf16
    const float* __restrict__ gbhh,            // [6144]
    const float* __restrict__ xw_t,            // [32][8192]
    const unsigned short* __restrict__ hbf_in, // [32][2048]
    const unsigned short* __restrict__ hgbf,   // [32][2048]
    float* __restrict__ c32,                   // [32][2048] in/out
    unsigned short* __restrict__ cbf,          // [32][2048] out
    unsigned short* __restrict__ hbf_out,      // [32][2048] out
    float* __restrict__ gh)                    // [32][6144] out (raw + bhh)
{
    __shared__ float lsum[4][4][32][17];
    const int tid = threadIdx.x;
    const int lane = tid & 63;
    const int w = tid >> 6;       // 0..15
    const int g = w >> 2;         // gate (LSTM) / strip (GRU)
    const int kh = w & 3;         // K quarter
    const int l15 = lane & 15;
    const int lq = lane >> 4;     // 0..3
    const int kofs = kh * 512 + lq * 8;

    const bool lstm = (blockIdx.x < 128);
    const unsigned short* Abase;
    const unsigned short* Brow;
    if (lstm) {
        int kk0 = blockIdx.x * 16;
        Brow = Whh + (size_t)(g * HH + kk0 + l15) * HH + kofs;
        Abase = hbf_in;
    } else {
        int n0 = (blockIdx.x - 128) * 64;
        Brow = gWhh + (size_t)(n0 + g * 16 + l15) * HH + kofs;
        Abase = hgbf;
    }
    const unsigned short* Arow0 = Abase + l15 * HH + kofs;
    const unsigned short* Arow1 = Arow0 + 16 * HH;

    f32x4 acc0 = {0.f, 0.f, 0.f, 0.f};
    f32x4 acc1 = {0.f, 0.f, 0.f, 0.f};
#pragma unroll 4
    for (int it = 0; it < 16; ++it) {
        s16x8 bv = *(const s16x8*)(Brow + it * 32);
        s16x8 a0 = *(const s16x8*)(Arow0 + it * 32);
        s16x8 a1 = *(const s16x8*)(Arow1 + it * 32);
        acc0 = __builtin_amdgcn_mfma_f32_16x16x32_bf16(a0, bv, acc0, 0, 0, 0);
        acc1 = __builtin_amdgcn_mfma_f32_16x16x32_bf16(a1, bv, acc1, 0, 0, 0);
    }
#pragma unroll
    for (int r = 0; r < 4; ++r) {
        lsum[g][kh][lq * 4 + r][l15]      = acc0[r];   // [gate][ksplit][batch][n]
        lsum[g][kh][16 + lq * 4 + r][l15] = acc1[r];
    }
    __syncthreads();

    if (lstm) {
        if (tid < 512) {
            int kk0 = blockIdx.x * 16;
            int kkl = tid & 15, b = tid >> 4;          // 512 = 32b x 16kk
            int kk = kk0 + kkl;
            const float* xwb = xw_t + (size_t)b * 4 * HH;
            float vi = lsum[0][0][b][kkl] + lsum[0][1][b][kkl] + lsum[0][2][b][kkl] + lsum[0][3][b][kkl] + xwb[kk];
            float vf = lsum[1][0][b][kkl] + lsum[1][1][b][kkl] + lsum[1][2][b][kkl] + lsum[1][3][b][kkl] + xwb[HH + kk];
            float vg = lsum[2][0][b][kkl] + lsum[2][1][b][kkl] + lsum[2][2][b][kkl] + lsum[2][3][b][kkl] + xwb[2 * HH + kk];
            float vo = lsum[3][0][b][kkl] + lsum[3][1][b][kkl] + lsum[3][2][b][kkl] + lsum[3][3][b][kkl] + xwb[3 * HH + kk];
            int idx = b * HH + kk;
            float c = sigmf(vf) * c32[idx] + sigmf(vi) * tanhf_fast(vg);
            float h = sigmf(vo) * tanhf_fast(c);
            c32[idx] = c;
            cbf[idx] = f2bf(c);
            hbf_out[idx] = f2bf(h);
        }
    } else {
        int n0 = (blockIdx.x - 128) * 64;
        for (int cell = tid; cell < 2048; cell += 1024) {
            int nl = cell & 63, b = cell >> 6;
            int s = nl >> 4, n15 = nl & 15;
            float v = lsum[s][0][b][n15] + lsum[s][1][b][n15] + lsum[s][2][b][n15] + lsum[s][3][b][n15]
                      + gbhh[n0 + nl];
            gh[b * 3 * HH + n0 + nl] = v;
        }
    }
}

// ---------------------------------------------------------------------------
// step2: gi = cbf @ gWih.T; one 16-kk strip, 3 gates x 4 K-quarters
// (12 waves, 768 threads), fused GRU epilogue.
// ---------------------------------------------------------------------------
__global__ __launch_bounds__(768, 3) void step2_kernel(
    const unsigned short* __restrict__ gWih,   // [6144][2048] bf16
    const float* __restrict__ gbih,            // [6144]
    const unsigned short* __restrict__ cbf,    // [32][2048]
    const float* __restrict__ gh,              // [32][6144]
    float* __restrict__ hg32,                  // [32][2048] in/out
    unsigned short* __restrict__ hgbf,         // [32][2048] out
    unsigned short* __restrict__ hg_all_t)     // rows b of hg_all[(t*32+b)][k]
{
    __shared__ float lsum[3][4][32][17];
    const int tid = threadIdx.x;
    const int lane = tid & 63;
    const int w = tid >> 6;       // 0..11
    const int g = w >> 2;         // 0..2 (r,z,n)
    const int kh = w & 3;
    const int l15 = lane & 15;
    const int lq = lane >> 4;
    const int kofs = kh * 512 + lq * 8;
    const int kk0 = blockIdx.x * 16;

    const unsigned short* Arow0 = cbf + l15 * HH + kofs;
    const unsigned short* Arow1 = Arow0 + 16 * HH;
    const unsigned short* Brow = gWih + (size_t)(g * HH + kk0 + l15) * HH + kofs;

    f32x4 acc0 = {0.f, 0.f, 0.f, 0.f};
    f32x4 acc1 = {0.f, 0.f, 0.f, 0.f};
#pragma unroll 4
    for (int it = 0; it < 16; ++it) {
        s16x8 bv = *(const s16x8*)(Brow + it * 32);
        s16x8 a0 = *(const s16x8*)(Arow0 + it * 32);
        s16x8 a1 = *(const s16x8*)(Arow1 + it * 32);
        acc0 = __builtin_amdgcn_mfma_f32_16x16x32_bf16(a0, bv, acc0, 0, 0, 0);
        acc1 = __builtin_amdgcn_mfma_f32_16x16x32_bf16(a1, bv, acc1, 0, 0, 0);
    }
#pragma unroll
    for (int r = 0; r < 4; ++r) {
        lsum[g][kh][lq * 4 + r][l15]      = acc0[r];
        lsum[g][kh][16 + lq * 4 + r][l15] = acc1[r];
    }
    __syncthreads();

    if (tid < 512) {
        int kkl = tid & 15, b = tid >> 4;
        int kk = kk0 + kkl;
        float ri = lsum[0][0][b][kkl] + lsum[0][1][b][kkl] + lsum[0][2][b][kkl] + lsum[0][3][b][kkl] + gbih[kk];
        float zi = lsum[1][0][b][kkl] + lsum[1][1][b][kkl] + lsum[1][2][b][kkl] + lsum[1][3][b][kkl] + gbih[HH + kk];
        float ni = lsum[2][0][b][kkl] + lsum[2][1][b][kkl] + lsum[2][2][b][kkl] + lsum[2][3][b][kkl] + gbih[2 * HH + kk];
        const float* ghb = gh + b * 3 * HH;
        float r = sigmf(ri + ghb[kk]);
        float z = sigmf(zi + ghb[HH + kk]);
        float n = tanhf_fast(ni + r * ghb[2 * HH + kk]);
        int idx = b * HH + kk;
        float hgn = (1.f - z) * n + z * hg32[idx];
        hg32[idx] = hgn;
        unsigned short hb = f2bf(hgn);
        hgbf[idx] = hb;
        hg_all_t[idx] = hb;
    }
}

// ---------------------------------------------------------------------------
// Phase C: out = hg_all @ linW.T + b. bf16 MFMA, 128x128 tile, BK=32.
// 256 threads = 4 waves; wave owns a 64x64 quadrant = 4x4 MFMA 16x16 tiles
// (m97 structure). grid (10 m-tiles, 63 n-tiles).
// ---------------------------------------------------------------------------
__global__ __launch_bounds__(256) void out_gemm_kernel(
    const unsigned short* __restrict__ A,     // [1280][2048] (rows >=1248 junk)
    const unsigned short* __restrict__ Wl,    // [8000][2048] (reads to 8063 ok)
    const float* __restrict__ bl,
    float* __restrict__ out) {
    __shared__ unsigned short As[128][32];
    __shared__ unsigned short Bs[128][32];
    const int tid = threadIdx.x;
    const int lane = tid & 63;
    const int w = tid >> 6;
    const int l15 = lane & 15;
    const int lq = lane >> 4;
    const int mt = blockIdx.x, nt = blockIdx.y;
    const int mq = w >> 1, nq = w & 1;

    // staging: thread tid stages linear chunks tid and tid+256 (16B each)
    const int row0 = tid >> 2, kc0 = (tid & 3) * 8;
    const unsigned short* Ap0 = A + (size_t)(mt * 128 + row0) * HH + kc0;
    const unsigned short* Ap1 = A + (size_t)(mt * 128 + 64 + row0) * HH + kc0;
    const unsigned short* Bp0 = Wl + (size_t)(nt * 128 + row0) * HH + kc0;
    const unsigned short* Bp1 = Wl + (size_t)(nt * 128 + 64 + row0) * HH + kc0;

    f32x4 acc[4][4];
#pragma unroll
    for (int i = 0; i < 4; ++i)
#pragma unroll
        for (int j = 0; j < 4; ++j) acc[i][j] = (f32x4){0.f, 0.f, 0.f, 0.f};

    for (int k0 = 0; k0 < HH; k0 += 32) {
        s16x8 a0v = *(const s16x8*)(Ap0 + k0);
        s16x8 a1v = *(const s16x8*)(Ap1 + k0);
        s16x8 b0v = *(const s16x8*)(Bp0 + k0);
        s16x8 b1v = *(const s16x8*)(Bp1 + k0);
        *(s16x8*)&As[row0][kc0]      = a0v;
        *(s16x8*)&As[64 + row0][kc0] = a1v;
        *(s16x8*)&Bs[row0][kc0]      = b0v;
        *(s16x8*)&Bs[64 + row0][kc0] = b1v;
        __syncthreads();
        s16x8 af[4], bf[4];
#pragma unroll
        for (int i = 0; i < 4; ++i) af[i] = *(const s16x8*)&As[mq * 64 + i * 16 + l15][lq * 8];
#pragma unroll
        for (int j = 0; j < 4; ++j) bf[j] = *(const s16x8*)&Bs[nq * 64 + j * 16 + l15][lq * 8];
#pragma unroll
        for (int i = 0; i < 4; ++i)
#pragma unroll
            for (int j = 0; j < 4; ++j)
                acc[i][j] = __builtin_amdgcn_mfma_f32_16x16x32_bf16(af[i], bf[j], acc[i][j], 0, 0, 0);
        __syncthreads();
    }
#pragma unroll
    for (int j = 0; j < 4; ++j) {
        int n = nt * 128 + nq * 64 + j * 16 + l15;
        float bn = bl[n < VV ? n : VV - 1];
#pragma unroll
        for (int i = 0; i < 4; ++i) {
#pragma unroll
            for (int r = 0; r < 4; ++r) {
                int m = mt * 128 + mq * 64 + i * 16 + lq * 4 + r;
                if (m < TS * BB && n < VV) {
                    int t = m >> 5, b = m & 31;
                    out[((size_t)b * TS + t) * VV + n] = acc[i][j][r] + bn;
                }
            }
        }
    }
}

// ---------------------------------------------------------------------------
extern "C" void kernel_launch(void* const* d_in, const int* in_sizes, int n_in,
                              void* d_out, int out_size, void* d_ws, size_t ws_size,
                              hipStream_t stream) {
    const float* features = (const float*)d_in[0];
    const int*   captions = (const int*)d_in[1];
    const float* emb      = (const float*)d_in[2];
    const float* lstm_Wih = (const float*)d_in[3];
    const float* lstm_bih = (const float*)d_in[4];
    const float* lstm_Whh = (const float*)d_in[5];
    const float* lstm_bhh = (const float*)d_in[6];
    const float* gru_Wih  = (const float*)d_in[7];
    const float* gru_bih  = (const float*)d_in[8];
    const float* gru_Whh  = (const float*)d_in[9];
    const float* gru_bhh  = (const float*)d_in[10];
    const float* lin_W    = (const float*)d_in[11];
    const float* lin_b    = (const float*)d_in[12];
    float* out = (float*)d_out;

    // workspace layout (bf16 section first, then fp32) — ~165 MB total
    unsigned short* us = (unsigned short*)d_ws;
    unsigned short* Whh_bf  = us;                              // 8192*2048
    unsigned short* gWhh_bf = Whh_bf  + (size_t)8192 * HH;     // 6144*2048
    unsigned short* gWih_bf = gWhh_bf + (size_t)6144 * HH;     // 6144*2048
    unsigned short* linW_bf = gWih_bf + (size_t)6144 * HH;     // 8000*2048
    unsigned short* hbf0    = linW_bf + (size_t)VV * HH;
    unsigned short* hbf1    = hbf0 + BB * HH;
    unsigned short* cbf     = hbf1 + BB * HH;
    unsigned short* hgbf    = cbf  + BB * HH;
    unsigned short* hg_all  = hgbf + BB * HH;                  // 1280*2048 (padded)
    float* f32s = (float*)(hg_all + (size_t)1280 * HH);
    float* xw   = f32s;                                        // 39*32*8192
    float* c32  = xw + (size_t)TS * BB * 4 * HH;
    float* hg32 = c32 + BB * HH;
    float* gh   = hg32 + BB * HH;                              // 32*6144

    // 1) weight conversion (d_ws is re-poisoned before every call)
    {
        int n4;
        n4 = 8192 * HH / 4;
        convert_kernel<<<(n4 + 255) / 256, 256, 0, stream>>>(lstm_Whh, Whh_bf, n4);
        n4 = 6144 * HH / 4;
        convert_kernel<<<(n4 + 255) / 256, 256, 0, stream>>>(gru_Whh, gWhh_bf, n4);
        convert_kernel<<<(n4 + 255) / 256, 256, 0, stream>>>(gru_Wih, gWih_bf, n4);
        n4 = VV * HH / 4;
        convert_kernel<<<(n4 + 255) / 256, 256, 0, stream>>>(lin_W, linW_bf, n4);
    }

    // 2) precompute x-side gate biases for all steps
    embed_proj_kernel<<<dim3(4 * HH / 256, TS), 256, 0, stream>>>(
        captions, emb, lstm_Wih, lstm_bih, lstm_bhh, xw);

    // 3) init states
    init_state_kernel<<<(BB * HH) / 256, 256, 0, stream>>>(
        features, c32, hg32, hbf0, cbf, hgbf);

    // 4) recurrence
    for (int t = 0; t < TS; ++t) {
        const unsigned short* hin = (t & 1) ? hbf1 : hbf0;
        unsigned short*       hout = (t & 1) ? hbf0 : hbf1;
        step1_kernel<<<224, 1024, 0, stream>>>(
            Whh_bf, gWhh_bf, gru_bhh, xw + (size_t)t * BB * 4 * HH,
            hin, hgbf, c32, cbf, hout, gh);
        step2_kernel<<<128, 768, 0, stream>>>(
            gWih_bf, gru_bih, cbf, gh, hg32, hgbf, hg_all + (size_t)t * BB * HH);
    }

    // 5) output projection
    out_gemm_kernel<<<dim3((TS * BB + 127) / 128, (VV + 127) / 128), 256, 0, stream>>>(
        hg_all, linW_bf, lin_b, out);
}